// Round 23
// baseline (154.403 us; speedup 1.0000x reference)
//
#include <hip/hip_runtime.h>
#include <math.h>

#define N_QUBITS 24
#define N_BLOCKS 4
#define NSTATE (1 << N_QUBITS)

// Qubit q <-> flat bit (23-q). Per block: RY(0); q=1..23: RY(q); CNOT(q-1,q).
// 5-dispatch schedule (span-repacked, 576 MB total):
//  F: b0 analytic + b1 q0..14   span {e9..23}            -> out  (write-only)
//  A: b1 q15..23 + b2 q0..5     span {e0..8}u{e18..23}   out -> ws
//  B: b2 q6..20                 span {e3..17} (e18 diag) ws -> out
//  C: b2 q21..23 + b3 q0..8     span {e0..5}u{e15..23}   out -> ws
//  D: b3 q9..23 + SQUARE        span {e0..14} (e15 diag) ws -> out (std layout)
// R23: A/B/C use __launch_bounds__(1024, 1) -> 1 wg/CU guaranteed -> 128-VGPR
// bracket (m69 wave-slot quantization). R21/R22's 64-VGPR bracket spilled
// kernB's a[32] (VGPR=36, 44us). F/D keep (1024,2) (proven spill-free).

// ---- VALU lane-exchange primitives (R17/R20-proven) ----
template <int CTRL>
__device__ __forceinline__ float dpp_mov(float v) {
    return __int_as_float(__builtin_amdgcn_update_dpp(
        __float_as_int(v), __float_as_int(v), CTRL, 0xF, 0xF, false));
}
template <int MASK>
__device__ __forceinline__ float xor_lanes(float v, int lane) {
    if constexpr (MASK == 1)       return dpp_mov<0xB1>(v);   // quad_perm [1,0,3,2]
    else if constexpr (MASK == 2)  return dpp_mov<0x4E>(v);   // quad_perm [2,3,0,1]
    else if constexpr (MASK == 4) {
        float lo = dpp_mov<0x114>(v);   // row_shr:4 -> dst[i] = src[i-4]
        float hi = dpp_mov<0x104>(v);   // row_shl:4 -> dst[i] = src[i+4]
        return (lane & 4) ? lo : hi;
    }
    else if constexpr (MASK == 8)  return dpp_mov<0x128>(v);  // row_ror:8 == xor 8
    else                           return __shfl_xor(v, MASK);
}

// ---- 32-reg gate helpers (proven) ----
template <int B>
__device__ __forceinline__ void pair_bit32(float (&a)[32], float s, float c, int swap) {
#pragma unroll
    for (int g = 0; g < 16; ++g) {
        int r0 = ((g >> B) << (B + 1)) | (g & ((1 << B) - 1));
        int r1 = r0 | (1 << B);
        float v0 = a[r0], v1 = a[r1];
        float o0 = c * v0 - s * v1;
        float o1 = s * v0 + c * v1;
        a[r0] = swap ? o1 : o0;
        a[r1] = swap ? o0 : o1;
    }
}
template <int BT>
__device__ __forceinline__ void quad_gate32(float (&a)[32], float s, float c) {
#pragma unroll
    for (int g = 0; g < 8; ++g) {
        int lo  = g & ((1 << BT) - 1);
        int r00 = ((g >> BT) << (BT + 2)) | lo;
        int r01 = r00 | (1 << BT);
        int r10 = r00 | (2 << BT);
        int r11 = r00 | (3 << BT);
        float v00 = a[r00], v01 = a[r01], v10 = a[r10], v11 = a[r11];
        a[r00] = c * v00 - s * v01;
        a[r01] = s * v00 + c * v01;
        a[r10] = s * v10 + c * v11;
        a[r11] = c * v10 - s * v11;
    }
}
// RY+CNOT with tgt = reg bit 4, ctrl = reg bit 0.
__device__ __forceinline__ void pair_ctrl_reg0(float (&a)[32], float s, float c) {
#pragma unroll
    for (int g = 0; g < 16; ++g) {
        float v0 = a[g], v1 = a[g | 16];
        float o0 = c * v0 - s * v1;
        float o1 = s * v0 + c * v1;
        if (g & 1) { a[g] = o1; a[g | 16] = o0; }
        else       { a[g] = o0; a[g | 16] = o1; }
    }
}
// Fused RY+CNOT lane gate: tgt = lane bit of MASK, ctrl = lane bit of 2*MASK.
template <int MASK>
__device__ __forceinline__ void lane_gate32(float (&a)[32], float s, float c, int lane) {
    const int tau = (lane & MASK) ? 1 : 0;
    const int gam = (lane & (MASK << 1)) ? 1 : 0;
    const float A = gam ? (tau ? -s : s) : c;
    const float B = gam ? c : (tau ? s : -s);
#pragma unroll
    for (int r = 0; r < 32; ++r) {
        float p = xor_lanes<MASK>(a[r], lane);
        a[r] = A * a[r] + B * p;
    }
}
// RY-only lane gate on lane bit of MASK.
template <int MASK>
__device__ __forceinline__ void lane_ry32(float (&a)[32], float s, float c, int lane) {
    const int tau = (lane & MASK) ? 1 : 0;
    const float A = c, B = tau ? s : -s;
#pragma unroll
    for (int r = 0; r < 32; ++r) {
        float p = xor_lanes<MASK>(a[r], lane);
        a[r] = A * a[r] + B * p;
    }
}
// Lane gate, tgt = lane bit of MASK, ctrl = reg bit 0.
template <int MASK>
__device__ __forceinline__ void lane_gate32_regctrl(float (&a)[32], float s, float c,
                                                    int lane, int tau) {
    const float A0 = c,            B0 = tau ? s : -s;
    const float A1 = tau ? -s : s, B1 = c;
#pragma unroll
    for (int r = 0; r < 32; ++r) {
        float p = xor_lanes<MASK>(a[r], lane);
        float A = (r & 1) ? A1 : A0;
        float B = (r & 1) ? B1 : B0;
        a[r] = A * a[r] + B * p;
    }
}

// Identity chunked transpose (chunk = reg bit 4): swap reg bits0..3 <-> w.
#define IDT_TRANSPOSE(a, lds, lane, w)                                   \
    _Pragma("unroll")                                                    \
    for (int x = 0; x < 2; ++x) {                                        \
        __syncthreads();                                                 \
        _Pragma("unroll")                                                \
        for (int j = 0; j < 16; ++j)                                     \
            lds[(lane) | ((w) << 6) | (j << 10)] = a[(x << 4) | j];      \
        __syncthreads();                                                 \
        _Pragma("unroll")                                                \
        for (int m = 0; m < 16; ++m)                                     \
            a[(x << 4) | m] = lds[(lane) | (m << 6) | ((w) << 10)];      \
    }

// =========================== Kernel F ===========================
// b0 analytic + b1 q0..14. Span {e9..23}; blk = e0..8. No global reads.
__global__ __launch_bounds__(1024, 2)
void kernF(float* __restrict__ dst, const float* __restrict__ angles) {
    __shared__ float lds[16384];
    __shared__ float s0[24], c0[24], s1[15], c1[15];
    const int tid  = threadIdx.x;
    const int lane = tid & 63;
    const int w    = tid >> 6;
    const int blk  = blockIdx.x;                 // e0..8

    if (tid < 24) {
        float s, c; sincosf(0.5f * angles[tid], &s, &c);
        s0[tid] = s; c0[tid] = c;
    } else if (tid >= 32 && tid < 47) {
        float s, c; sincosf(0.5f * angles[24 + (tid - 32)], &s, &c);
        s1[tid - 32] = s; c1[tid - 32] = c;
    }

    // f10 sim (b0 q0..9) in lds[0..1023]; f bit k = e(14+k), qubit q -> bit 9-q.
    float* f = lds;
    f[tid] = 0.0f;
    __syncthreads();
    if (tid == 0) f[0] = 1.0f;
    __syncthreads();
    if (tid < 512) {
        float s = s0[0], c = c0[0];
        float v0 = f[tid], v1 = f[tid | 512];
        f[tid] = c * v0 - s * v1;
        f[tid | 512] = s * v0 + c * v1;
    }
    __syncthreads();
    for (int q = 1; q <= 9; ++q) {
        int bt = 9 - q;
        if (tid < 256) {
            float s = s0[q], c = c0[q];
            int lo  = tid & ((1 << bt) - 1);
            int r00 = ((tid >> bt) << (bt + 2)) | lo;
            int r01 = r00 | (1 << bt);
            int r10 = r00 | (2 << bt);
            int r11 = r00 | (3 << bt);
            float v00 = f[r00], v01 = f[r01], v10 = f[r10], v11 = f[r11];
            f[r00] = c * v00 - s * v01;
            f[r01] = s * v00 + c * v01;
            f[r10] = s * v10 + c * v11;
            f[r11] = c * v10 - s * v11;
        }
        __syncthreads();
    }

    float gfix = 1.0f;
#pragma unroll
    for (int j = 0; j < 8; ++j) {                // q23..q16: blk-only bits
        int x = ((blk >> j) ^ (blk >> (j + 1))) & 1;
        gfix *= x ? s0[23 - j] : c0[23 - j];
    }
    const float fval = f[w | (lane << 4)];
    const int b8 = (blk >> 8) & 1;
    const int w0 = w & 1;                        // e14

    float a[32];
#pragma unroll
    for (int r = 0; r < 32; ++r) {
        const int r0 = r & 1, r1 = (r >> 1) & 1, r2 = (r >> 2) & 1,
                  r3 = (r >> 3) & 1, r4 = (r >> 4) & 1;
        float g = gfix;
        g *= (b8 ^ r0) ? s0[15] : c0[15];
        g *= (r0 ^ r1) ? s0[14] : c0[14];
        g *= (r1 ^ r2) ? s0[13] : c0[13];
        g *= (r2 ^ r3) ? s0[12] : c0[12];
        g *= (r3 ^ r4) ? s0[11] : c0[11];
        g *= (r4 ^ w0) ? s0[10] : c0[10];
        a[r] = fval * g;
    }

    lane_ry32<32>(a, s1[0], c1[0], lane);        // q0 RY e23
    lane_gate32<16>(a, s1[1], c1[1], lane);      // q1
    lane_gate32<8>(a, s1[2], c1[2], lane);       // q2
    lane_gate32<4>(a, s1[3], c1[3], lane);       // q3
    lane_gate32<2>(a, s1[4], c1[4], lane);       // q4
    lane_gate32<1>(a, s1[5], c1[5], lane);       // q5

    IDT_TRANSPOSE(a, lds, lane, w)               // T_F (chunk e13@r4)

    pair_bit32<3>(a, s1[6], c1[6], lane & 1);    // q6: tgt e17, ctrl e18
    quad_gate32<2>(a, s1[7], c1[7]);             // q7
    quad_gate32<1>(a, s1[8], c1[8]);             // q8
    quad_gate32<0>(a, s1[9], c1[9]);             // q9
    pair_ctrl_reg0(a, s1[10], c1[10]);           // q10: tgt e13(r4), ctrl e14(r0)

    IDT_TRANSPOSE(a, lds, lane, w)               // T2_F (chunk e13)

    quad_gate32<3>(a, s1[11], c1[11]);           // q11
    quad_gate32<2>(a, s1[12], c1[12]);           // q12
    quad_gate32<1>(a, s1[13], c1[13]);           // q13
    quad_gate32<0>(a, s1[14], c1[14]);           // q14

#pragma unroll
    for (int m = 0; m < 32; ++m)
        dst[((size_t)blk << 15) | lane | (w << 6) | ((m & 15) << 10)
            | ((m >> 4) << 14)] = a[m];
}

// =========================== Kernel A ===========================
// b1 q15..23 + b2 q0..5. Span {e0..8}u{e18..23}; blk = e9..17.
__global__ __launch_bounds__(1024, 1)
void kernA(const float* __restrict__ src, float* __restrict__ dst,
           const float* __restrict__ angles) {
    __shared__ float lds[16384];
    __shared__ float scs[15], scc[15];
    const int tid  = threadIdx.x;
    const int lane = tid & 63;
    const int w    = tid >> 6;
    const int blk  = blockIdx.x;                 // e9..17

    if (tid < 9) {          // b1 q15..23
        float s, c; sincosf(0.5f * angles[24 + 15 + tid], &s, &c);
        scs[tid] = s; scc[tid] = c;
    } else if (tid >= 16 && tid < 22) {          // b2 q0..5
        float s, c; sincosf(0.5f * angles[48 + (tid - 16)], &s, &c);
        scs[9 + tid - 16] = s; scc[9 + tid - 16] = c;
    }

    float a[32];
    const int hi4 = blk >> 5, lo4 = blk & 15, b13 = (blk >> 4) & 1;
#pragma unroll
    for (int r = 0; r < 32; ++r) {
        int Fblk = ((r >> 4) & 1) | (w << 1) | ((r & 15) << 5);
        a[r] = src[((size_t)Fblk << 15) | lane | (hi4 << 6) | (lo4 << 10)
                   | (b13 << 14)];
    }
    __syncthreads();

    pair_bit32<3>(a, scs[0], scc[0], blk & 1);   // q15: tgt e8, ctrl e9 (diag)
    quad_gate32<2>(a, scs[1], scc[1]);           // q16
    quad_gate32<1>(a, scs[2], scc[2]);           // q17
    quad_gate32<0>(a, scs[3], scc[3]);           // q18

    IDT_TRANSPOSE(a, lds, lane, w)               // T_A (chunk e0@r4)

    pair_bit32<3>(a, scs[4], scc[4], w & 1);     // q19: tgt e4, ctrl e5
    quad_gate32<2>(a, scs[5], scc[5]);           // q20
    quad_gate32<1>(a, scs[6], scc[6]);           // q21
    quad_gate32<0>(a, scs[7], scc[7]);           // q22
    pair_ctrl_reg0(a, scs[8], scc[8]);           // q23: tgt e0(r4), ctrl e1(r0)

    lane_ry32<32>(a, scs[9], scc[9], lane);      // b2 q0 RY e23
    lane_gate32<16>(a, scs[10], scc[10], lane);  // q1
    lane_gate32<8>(a, scs[11], scc[11], lane);   // q2
    lane_gate32<4>(a, scs[12], scc[12], lane);   // q3
    lane_gate32<2>(a, scs[13], scc[13], lane);   // q4
    lane_gate32<1>(a, scs[14], scc[14], lane);   // q5

    // T_A2 + write (chunk e0 = reg bit 4), swizzled; hoisted constants.
    const int W37 = (w & 7) << 2;
    const int LW  = (lane & 31) ^ W37;
    const int HA  = (((lane >> 5) & 1) << 5) | (((w >> 3) & 1) << 6) | (W37 << 7);
    const int RW  = W37 ^ (lane & 31);
    const int HR  = (((w >> 3) & 1) << 5) | (((lane >> 5) & 1) << 6)
                  | ((lane & 31) << 7);
    const size_t DA = ((size_t)blk << 15) | (size_t)lane | ((size_t)w << 11);
#pragma unroll
    for (int x = 0; x < 2; ++x) {
        __syncthreads();
#pragma unroll
        for (int jj = 0; jj < 16; ++jj) {        // regs (x<<4)|jj; jj = e1..4
            int j2 = jj >> 2;
            int h = (LW ^ j2) | HA | (j2 << 7)
                  | ((jj & 1) << 12) | (((jj >> 1) & 1) << 13);
            lds[h] = a[(x << 4) | jj];
        }
        __syncthreads();
#pragma unroll
        for (int mm = 0; mm < 16; ++mm) {        // L2 regs: mm=(e1,e2,e18,e19)
            int m2 = ((mm >> 2) & 1) | (((mm >> 3) & 1) << 1);
            int h = (RW ^ m2) | HR | ((mm & 1) << 12) | (((mm >> 1) & 1) << 13);
            float v = lds[h];
            dst[DA | (x << 6) | ((mm & 1) << 7) | (((mm >> 1) & 1) << 8)
                | (((mm >> 2) & 1) << 9) | (((mm >> 3) & 1) << 10)] = v;
        }
    }
}

// =========================== Kernel B ===========================
// b2 q6..20. Span {e3..17}; blk: [0..2]=e0..2, [3]=e18, [4]=e19, [5..8]=e20..23.
__global__ __launch_bounds__(1024, 1)
void kernB(const float* __restrict__ src, float* __restrict__ dst,
           const float* __restrict__ angles) {
    __shared__ float lds[16384];
    __shared__ float scs[15], scc[15];
    const int tid  = threadIdx.x;
    const int lane = tid & 63;
    const int w    = tid >> 6;
    const int blk  = blockIdx.x;

    if (tid < 15) {                              // b2 q6..20
        float s, c; sincosf(0.5f * angles[48 + 6 + tid], &s, &c);
        scs[tid] = s; scc[tid] = c;
    }

    float a[32];
    const int fixedA = ((blk & 1) << 6) | (((blk >> 1) & 1) << 7)
                     | (((blk >> 2) & 1) << 8) | (((blk >> 3) & 1) << 9)
                     | (((blk >> 4) & 1) << 10) | ((blk >> 5) << 11);
#pragma unroll
    for (int r = 0; r < 32; ++r) {
        int Ablk = w | (r << 4);                 // e9..12=w, e13..17=r
        a[r] = src[((size_t)Ablk << 15) | lane | fixedA];
    }
    __syncthreads();

    pair_bit32<4>(a, scs[0], scc[0], (blk >> 3) & 1);  // q6: tgt e17, ctrl e18 diag
    quad_gate32<3>(a, scs[1], scc[1]);           // q7
    quad_gate32<2>(a, scs[2], scc[2]);           // q8
    quad_gate32<1>(a, scs[3], scc[3]);           // q9
    quad_gate32<0>(a, scs[4], scc[4]);           // q10

    IDT_TRANSPOSE(a, lds, lane, w)               // T1_B (chunk e17@r4)

    pair_bit32<3>(a, scs[5], scc[5], w & 1);     // q11: tgt e12, ctrl e13
    quad_gate32<2>(a, scs[6], scc[6]);           // q12
    quad_gate32<1>(a, scs[7], scc[7]);           // q13
    quad_gate32<0>(a, scs[8], scc[8]);           // q14
    lane_gate32_regctrl<32>(a, scs[9], scc[9], lane, (lane >> 5) & 1); // q15
    lane_gate32<16>(a, scs[10], scc[10], lane);  // q16
    lane_gate32<8>(a, scs[11], scc[11], lane);   // q17
    lane_gate32<4>(a, scs[12], scc[12], lane);   // q18
    lane_gate32<2>(a, scs[13], scc[13], lane);   // q19
    lane_gate32<1>(a, scs[14], scc[14], lane);   // q20

    // T_B2 + write (chunk e9 = reg bit 0), swizzled; hoisted constants.
    const int WB = (lane & 7)
                 | ((((lane >> 3) & 1) ^ ((w >> 2) & 1)) << 3)
                 | ((((lane >> 4) & 1) ^ ((w >> 3) & 1)) << 4)
                 | (((lane >> 5) & 1) << 5)
                 | (((w >> 2) & 1) << 6) | (((w >> 3) & 1) << 7)
                 | ((w & 1) << 12) | (((w >> 1) & 1) << 13);
    const int RB = (lane & 7)
                 | (((w & 1) ^ ((lane >> 3) & 1)) << 3)
                 | ((((w >> 1) & 1) ^ ((lane >> 4) & 1)) << 4)
                 | (((w >> 2) & 1) << 5)
                 | (((lane >> 3) & 1) << 6) | (((lane >> 4) & 1) << 7)
                 | (((lane >> 5) & 1) << 8) | (((w >> 3) & 1) << 13);
    const size_t DB = ((size_t)blk << 15) | (size_t)lane | ((size_t)(w & 7) << 6)
                    | ((size_t)((w >> 3) & 1) << 14);
#pragma unroll
    for (int x = 0; x < 2; ++x) {
        __syncthreads();
#pragma unroll
        for (int jj = 0; jj < 16; ++jj) {        // regs (jj<<1)|x; jj: e10..12, e17
            int h = WB | (((jj >> 3) & 1) << 8) | ((jj & 7) << 9);
            lds[h] = a[(jj << 1) | x];
        }
        __syncthreads();
#pragma unroll
        for (int mm = 0; mm < 16; ++mm) {        // L2 regs (mm<<1)|x; mm: e10..12, e13
            int h = RB | ((mm & 7) << 9) | (((mm >> 3) & 1) << 12);
            float v = lds[h];
            dst[DB | (x << 9) | ((mm & 7) << 10) | (((mm >> 3) & 1) << 13)] = v;
        }
    }
}

// =========================== Kernel C ===========================
// b2 q21..23 + b3 q0..8. Span {e0..5}u{e15..23}; blk = e6..14.
__global__ __launch_bounds__(1024, 1)
void kernC(const float* __restrict__ src, float* __restrict__ dst,
           const float* __restrict__ angles) {
    __shared__ float lds[16384];
    __shared__ float scs[12], scc[12];
    const int tid  = threadIdx.x;
    const int lane = tid & 63;
    const int w    = tid >> 6;
    const int blk  = blockIdx.x;                 // e6..14

    if (tid < 3) {                               // b2 q21..23
        float s, c; sincosf(0.5f * angles[48 + 21 + tid], &s, &c);
        scs[tid] = s; scc[tid] = c;
    } else if (tid >= 8 && tid < 17) {           // b3 q0..8
        float s, c; sincosf(0.5f * angles[72 + (tid - 8)], &s, &c);
        scs[3 + tid - 8] = s; scc[3 + tid - 8] = c;
    }

    float a[32];
    const int fixedB = ((blk & 7) << 6) | (((blk >> 3) & 15) << 9)
                     | (((blk >> 7) & 1) << 13) | (((blk >> 8) & 1) << 14);
#pragma unroll
    for (int r = 0; r < 32; ++r) {
        int Bblk = (r & 31) | (w << 5);          // e0..2,e18,e19 = r; e20..23 = w
        a[r] = src[((size_t)Bblk << 15) | lane | fixedB];
    }
    __syncthreads();

    pair_bit32<2>(a, scs[0], scc[0], lane & 1);  // q21: tgt e2, ctrl e3 (lane0)
    quad_gate32<1>(a, scs[1], scc[1]);           // q22
    quad_gate32<0>(a, scs[2], scc[2]);           // q23

    IDT_TRANSPOSE(a, lds, lane, w)               // T_C (chunk e19@r4)

    pair_bit32<3>(a, scs[3], scc[3], 0);         // b3 q0: RY tgt e23
    quad_gate32<2>(a, scs[4], scc[4]);           // q1
    quad_gate32<1>(a, scs[5], scc[5]);           // q2
    quad_gate32<0>(a, scs[6], scc[6]);           // q3
    pair_ctrl_reg0(a, scs[7], scc[7]);           // q4: tgt e19(r4), ctrl e20(r0)

    // T_C3 (chunk e19 = reg bit 4), swizzled; hoisted constants.
    const int WC = (lane & 7)
                 | ((((lane >> 3) & 1) ^ (w & 1)) << 3)
                 | ((((lane >> 4) & 1) ^ ((w >> 1) & 1)) << 4)
                 | (((lane >> 5) & 1) << 5)
                 | (((lane >> 3) & 1) << 6) | (((lane >> 4) & 1) << 7)
                 | (((w >> 3) & 1) << 8) | (((w >> 2) & 1) << 9);
    const int RC = ((lane >> 3) & 7) | ((lane & 1) << 3) | (((lane >> 1) & 1) << 4)
                 | (((lane >> 2) & 1) << 9) | (w << 10);
#pragma unroll
    for (int x = 0; x < 2; ++x) {
        __syncthreads();
#pragma unroll
        for (int jj = 0; jj < 16; ++jj) {        // regs (x<<4)|jj; jj = e20..23
            lds[WC | (jj << 10)] = a[(x << 4) | jj];
        }
        __syncthreads();
#pragma unroll
        for (int mm = 0; mm < 16; ++mm) {        // L2 regs (x<<4)|mm; mm = e15..18
            int h = (RC ^ ((mm & 1) << 3) ^ ((((mm >> 1) & 1)) << 4))
                  | (((mm >> 2) & 1) << 5) | ((mm & 1) << 6)
                  | (((mm >> 1) & 1) << 7) | (((mm >> 3) & 1) << 8);
            a[(x << 4) | mm] = lds[h];
        }
    }

    quad_gate32<3>(a, scs[8], scc[8]);           // q5: tgt e18 ctrl e19
    quad_gate32<2>(a, scs[9], scc[9]);           // q6
    quad_gate32<1>(a, scs[10], scc[10]);         // q7
    quad_gate32<0>(a, scs[11], scc[11]);         // q8

#pragma unroll
    for (int m = 0; m < 32; ++m)
        dst[((size_t)blk << 15) | lane | ((m & 15) << 6) | ((m >> 4) << 10)
            | (w << 11)] = a[m];
}

// =========================== Kernel D ===========================
// b3 q9..23 + SQUARE. Span {e0..14}; blk = e15..23. Read hC; write STANDARD.
__global__ __launch_bounds__(1024, 2)
void kernD(const float* __restrict__ src, float* __restrict__ dst,
           const float* __restrict__ angles) {
    __shared__ float lds[16384];
    __shared__ float scs[15], scc[15];
    const int tid  = threadIdx.x;
    const int lane = tid & 63;
    const int w    = tid >> 6;
    const int blk  = blockIdx.x;                 // e15..23

    if (tid < 15) {                              // b3 q9..23
        float s, c; sincosf(0.5f * angles[72 + 9 + tid], &s, &c);
        scs[tid] = s; scc[tid] = c;
    }

    float a[32];
#pragma unroll
    for (int r = 0; r < 32; ++r) {
        int Cblk = w | (r << 4);                 // e6..9=w, e10..14=r
        a[r] = src[((size_t)Cblk << 15) | lane | (blk << 6)];
    }
    __syncthreads();

    pair_bit32<4>(a, scs[0], scc[0], blk & 1);   // q9: tgt e14, ctrl e15 diag
    quad_gate32<3>(a, scs[1], scc[1]);           // q10
    quad_gate32<2>(a, scs[2], scc[2]);           // q11
    quad_gate32<1>(a, scs[3], scc[3]);           // q12
    quad_gate32<0>(a, scs[4], scc[4]);           // q13

    IDT_TRANSPOSE(a, lds, lane, w)               // T1_D (chunk e14@r4)

    pair_bit32<3>(a, scs[5], scc[5], w & 1);     // q14: tgt e9, ctrl e10
    quad_gate32<2>(a, scs[6], scc[6]);           // q15
    quad_gate32<1>(a, scs[7], scc[7]);           // q16
    quad_gate32<0>(a, scs[8], scc[8]);           // q17
    lane_gate32_regctrl<32>(a, scs[9], scc[9], lane, (lane >> 5) & 1); // q18
    lane_gate32<16>(a, scs[10], scc[10], lane);  // q19
    lane_gate32<8>(a, scs[11], scc[11], lane);   // q20
    lane_gate32<4>(a, scs[12], scc[12], lane);   // q21
    lane_gate32<2>(a, scs[13], scc[13], lane);   // q22
    lane_gate32<1>(a, scs[14], scc[14], lane);   // q23

#pragma unroll
    for (int r = 0; r < 32; ++r) a[r] *= a[r];   // SQUARE

#pragma unroll
    for (int m = 0; m < 32; ++m)
        dst[((size_t)blk << 15) | ((m >> 4) << 14) | (w << 10) | ((m & 15) << 6)
            | lane] = a[m];
}

extern "C" void kernel_launch(void* const* d_in, const int* in_sizes, int n_in,
                              void* d_out, int out_size, void* d_ws, size_t ws_size,
                              hipStream_t stream) {
    const float* angles = (const float*)d_in[0];
    float* out = (float*)d_out;
    float* ws  = (float*)d_ws;

    kernF<<<512, 1024, 0, stream>>>(out, angles);        // -> out (hF)
    kernA<<<512, 1024, 0, stream>>>(out, ws, angles);    // out -> ws (hA)
    kernB<<<512, 1024, 0, stream>>>(ws, out, angles);    // ws -> out (hB)
    kernC<<<512, 1024, 0, stream>>>(out, ws, angles);    // out -> ws (hC)
    kernD<<<512, 1024, 0, stream>>>(ws, out, angles);    // ws -> out (std)
}

// Round 24
// 140.363 us; speedup vs baseline: 1.1000x; 1.1000x over previous
//
#include <hip/hip_runtime.h>
#include <math.h>

#define N_QUBITS 24
#define N_BLOCKS 4
#define NSTATE (1 << N_QUBITS)

// Qubit q <-> flat-index bit (23 - q).
// Per block (by commutation): RY(0); for q=1..23: RY(q); CNOT(q-1,q)
// Ping-pong buffers, alternating layouts (race-free: src != dst).
//   standard: addr = e23..e0
//   pi2:      addr = blk<<15 | G<<5 | e0..4,  blk = e5..13, G bit k = e(14+k)
// Schedule (6 dispatches, 704 MB — measured-best R20 configuration, 140 us):
//   fused   : block0 analytic product state x block1 q0..9 -> d_ws pi2 (W only)
//   P23(1)  : d_ws -> d_out ;  P1(2): d_out -> d_ws ;  P23(2): d_ws -> d_out
//   P1(3)   : d_out -> d_ws ;  P23(3)+SQUARE: d_ws -> d_out
// Lane-xor gates on VALU: masks 1/2/8 DPP; mask 4 DPP row_shr:4/row_shl:4 +
// select (row_shr:N -> dst[i]=src[i-N], row_shl:N -> dst[i]=src[i+N]);
// masks 16/32 __shfl_xor (ds_swizzle). Per-workgroup LDS sin/cos tables.
// [R21-R23 falsified a 5-pass span-repacked schedule: 576 MB but ~154 us —
//  scattered 32KiB-granule reads + extra swizzled transposes + 1 wg/CU lose
//  more than the 128 MB traffic saving. Keep the 6-pass structure.]

// ---- VALU lane-exchange primitives ----
template <int CTRL>
__device__ __forceinline__ float dpp_mov(float v) {
    return __int_as_float(__builtin_amdgcn_update_dpp(
        __float_as_int(v), __float_as_int(v), CTRL, 0xF, 0xF, false));
}
template <int MASK>
__device__ __forceinline__ float xor_lanes(float v, int lane) {
    if constexpr (MASK == 1)       return dpp_mov<0xB1>(v);   // quad_perm [1,0,3,2]
    else if constexpr (MASK == 2)  return dpp_mov<0x4E>(v);   // quad_perm [2,3,0,1]
    else if constexpr (MASK == 4) {
        float lo = dpp_mov<0x114>(v);   // row_shr:4 -> dst[i] = src[i-4] (i%16>=4)
        float hi = dpp_mov<0x104>(v);   // row_shl:4 -> dst[i] = src[i+4] (i%16<12)
        return (lane & 4) ? lo : hi;    // valid exactly where selected
    }
    else if constexpr (MASK == 8)  return dpp_mov<0x128>(v);  // row_ror:8 == xor 8
    else                           return __shfl_xor(v, MASK); // 16/32: ds_swizzle
}

// ---- 32-reg gate helpers ----
template <int B>
__device__ __forceinline__ void pair_bit32(float (&a)[32], float s, float c, int swap) {
#pragma unroll
    for (int g = 0; g < 16; ++g) {
        int r0 = ((g >> B) << (B + 1)) | (g & ((1 << B) - 1));
        int r1 = r0 | (1 << B);
        float v0 = a[r0], v1 = a[r1];
        float o0 = c * v0 - s * v1;
        float o1 = s * v0 + c * v1;
        a[r0] = swap ? o1 : o0;
        a[r1] = swap ? o0 : o1;
    }
}
// Fused RY(tgt = reg bit BT) then CNOT(ctrl = reg bit BT+1, tgt = reg bit BT).
template <int BT>
__device__ __forceinline__ void quad_gate32(float (&a)[32], float s, float c) {
#pragma unroll
    for (int g = 0; g < 8; ++g) {
        int lo  = g & ((1 << BT) - 1);
        int r00 = ((g >> BT) << (BT + 2)) | lo;
        int r01 = r00 | (1 << BT);
        int r10 = r00 | (2 << BT);
        int r11 = r00 | (3 << BT);
        float v00 = a[r00], v01 = a[r01], v10 = a[r10], v11 = a[r11];
        a[r00] = c * v00 - s * v01;
        a[r01] = s * v00 + c * v01;
        a[r10] = s * v10 + c * v11;   // ctrl=1 half: RY then swap (CNOT)
        a[r11] = c * v10 - s * v11;
    }
}
// Fused RY+CNOT lane gate: tgt = lane bit of MASK, ctrl = lane bit of 2*MASK.
template <int MASK>
__device__ __forceinline__ void lane_gate32(float (&a)[32], float s, float c, int lane) {
    const int tau = (lane & MASK) ? 1 : 0;
    const int gam = (lane & (MASK << 1)) ? 1 : 0;
    const float A = gam ? (tau ? -s : s) : c;
    const float B = gam ? c : (tau ? s : -s);
#pragma unroll
    for (int r = 0; r < 32; ++r) {
        float p = xor_lanes<MASK>(a[r], lane);
        a[r] = A * a[r] + B * p;
    }
}
// Lane gate with per-REG ctrl (reg bit 0): tgt = lane bit of MASK.
template <int MASK>
__device__ __forceinline__ void lane_gate32_regctrl(float (&a)[32], float s, float c,
                                                    int lane, int tau) {
    const float A0 = c,            B0 = tau ? s : -s;   // gam = 0 (even regs)
    const float A1 = tau ? -s : s, B1 = c;              // gam = 1 (odd regs)
#pragma unroll
    for (int r = 0; r < 32; ++r) {
        float p = xor_lanes<MASK>(a[r], lane);
        float A = (r & 1) ? A1 : A0;
        float B = (r & 1) ? B1 : B0;
        a[r] = A * a[r] + B * p;
    }
}

// Shared pass1 body: from a[] in L0 layout, apply qubits 0..9 of block `ang`,
// store pi2 to dst. L0: regs r = e19..23, w = e15..18, lane = (e0..4, e14@5).
// T1 (2 rounds by e23 = reg bit4 both sides; identity map, conflict-free):
//   L1: regs k = (e15..18 @0..3, e23@4), lane = (e0..4, e14@5), w = e19..22.
__device__ __forceinline__ void p1_body(float (&a)[32], float* __restrict__ lds,
                                        float* __restrict__ dst, int blk,
                                        const float* __restrict__ scs,
                                        const float* __restrict__ scc,
                                        int lane, int w) {
    pair_bit32<4>(a, scs[0], scc[0], 0);         // q0: tgt e23
    quad_gate32<3>(a, scs[1], scc[1]);           // q1: tgt e22 ctrl e23
    quad_gate32<2>(a, scs[2], scc[2]);
    quad_gate32<1>(a, scs[3], scc[3]);
    quad_gate32<0>(a, scs[4], scc[4]);           // q4: tgt e19 ctrl e20

    // T1: rounds x = e23; 16K floats/round (64 KiB LDS).
#pragma unroll
    for (int x = 0; x < 2; ++x) {
        __syncthreads();
#pragma unroll
        for (int j = 0; j < 16; ++j)
            lds[lane | (w << 6) | (j << 10)] = a[(x << 4) | j];
        __syncthreads();
#pragma unroll
        for (int m = 0; m < 16; ++m)
            a[(x << 4) | m] = lds[lane | (m << 6) | (w << 10)];
    }

    pair_bit32<3>(a, scs[5], scc[5], w & 1);     // q5: tgt e18 ctrl e19
    quad_gate32<2>(a, scs[6], scc[6]);           // q6: tgt e17 ctrl e18
    quad_gate32<1>(a, scs[7], scc[7]);           // q7: tgt e16 ctrl e17
    quad_gate32<0>(a, scs[8], scc[8]);           // q8: tgt e15 ctrl e16

    // q9: RY tgt e14 (lane bit 5) + CNOT ctrl e15 (reg bit 0): shfl mask 32.
    lane_gate32_regctrl<32>(a, scs[9], scc[9], lane, (lane >> 5) & 1);

    // store pi2: G = e14(lane5) | (k&15)<<1 [e15..18] | w<<5 [e19..22] | (k>>4)<<9 [e23]
#pragma unroll
    for (int k = 0; k < 32; ++k) {
        int G = ((lane >> 5) & 1) | ((k & 15) << 1) | (w << 5) | ((k >> 4) << 9);
        dst[((size_t)blk << 15) | (G << 5) | (size_t)(lane & 31)] = a[k];
    }
}

// ---------------- Pass 1 (std -> pi2): qubits 0..9 of block b ------------------
__global__ __launch_bounds__(1024, 2)
void pass1_pi_kernel(const float* __restrict__ src, float* __restrict__ dst,
                     const float* __restrict__ angles, int blk_b) {
    __shared__ float lds[16384];
    __shared__ float scs[10], scc[10];
    const int tid  = threadIdx.x;
    const int lane = tid & 63;
    const int w    = tid >> 6;                   // 0..15 = e15..18
    const int blk  = blockIdx.x;                 // e5..13 (9 bits)
    const float* ang = angles + blk_b * N_QUBITS;

    if (tid < 10) {
        float s, c;
        sincosf(0.5f * ang[tid], &s, &c);
        scs[tid] = s; scc[tid] = c;
    }

    float a[32];
    // read std: addr = r<<19 | w<<15 | (lane5=e14)<<14 | blk<<5 | lane&31
#pragma unroll
    for (int r = 0; r < 32; ++r)
        a[r] = src[((size_t)r << 19) | ((size_t)w << 15) | ((size_t)(lane >> 5) << 14)
                   | ((size_t)blk << 5) | (size_t)(lane & 31)];
    __syncthreads();                             // table ready

    p1_body(a, lds, dst, blk, scs, scc, lane, w);
}

// ---------------- Fused: block0 analytic + block1 qubits 0..9 -> pi2 -----------
// No global reads. f10 (1024 amps, block0 q0..9) via LDS sim; g via per-thread
// 14-factor product; a[r] = f10[(r<<5)|(w<<1)|e14] * g_c[blk<<5 | e0..4].
__global__ __launch_bounds__(1024, 2)
void fused_init_p1_kernel(float* __restrict__ dst, const float* __restrict__ angles) {
    __shared__ float lds[16384];
    __shared__ float s0[24], c0[24];             // block 0
    __shared__ float s1[10], c1[10];             // block 1
    const int tid  = threadIdx.x;
    const int lane = tid & 63;
    const int w    = tid >> 6;
    const int blk  = blockIdx.x;                 // e5..13

    if (tid < 24) {
        float s, c;
        sincosf(0.5f * angles[tid], &s, &c);
        s0[tid] = s; c0[tid] = c;
    } else if (tid >= 32 && tid < 42) {
        float s, c;
        sincosf(0.5f * angles[N_QUBITS + (tid - 32)], &s, &c);
        s1[tid - 32] = s; c1[tid - 32] = c;
    }

    // f10 sim in lds[0..1023]: index bit k = e(14+k); qubit q -> f bit (9-q).
    float* f = lds;
    f[tid] = 0.0f;
    __syncthreads();
    if (tid == 0) f[0] = 1.0f;
    __syncthreads();
    if (tid < 512) {                             // q0: tgt f bit 9 (e23)
        float s = s0[0], c = c0[0];
        float v0 = f[tid], v1 = f[tid | 512];
        f[tid] = c * v0 - s * v1;
        f[tid | 512] = s * v0 + c * v1;
    }
    __syncthreads();
    for (int q = 1; q <= 9; ++q) {
        int bt = 9 - q;                          // 8..0
        if (tid < 256) {
            float s = s0[q], c = c0[q];
            int lo  = tid & ((1 << bt) - 1);
            int r00 = ((tid >> bt) << (bt + 2)) | lo;
            int r01 = r00 | (1 << bt);
            int r10 = r00 | (2 << bt);
            int r11 = r00 | (3 << bt);
            float v00 = f[r00], v01 = f[r01], v10 = f[r10], v11 = f[r11];
            f[r00] = c * v00 - s * v01;
            f[r01] = s * v00 + c * v01;
            f[r10] = s * v10 + c * v11;
            f[r11] = c * v10 - s * v11;
        }
        __syncthreads();
    }

    // g_c[low14]: low = blk<<5 | (lane&31) (bits e0..13), chain seed c = e14.
    float gval = 1.0f;
    {
        const int low = (blk << 5) | (lane & 31);
        int prev = (lane >> 5) & 1;              // e14
#pragma unroll
        for (int q = 10; q <= 23; ++q) {
            const int bt = 23 - q;               // 13..0
            const int b = (low >> bt) & 1;
            gval *= (b ^ prev) ? s0[q] : c0[q];
            prev = b;
        }
    }

    // synthesize input amps (L0 layout): chunk = (r<<5)|(w<<1)|e14
    float a[32];
#pragma unroll
    for (int r = 0; r < 32; ++r)
        a[r] = f[(r << 5) | (w << 1) | (lane >> 5)] * gval;
    // (p1_body's first __syncthreads orders these f-reads before T1 overwrites lds)

    p1_body(a, lds, dst, blk, s1, c1, lane, w);
}

// ---------------- Pass 2+3 tail: qubits 10..23 on a 16384-float chunk ----------
// L0 (entry): regs r = e9..13, w = e6..8, lane = e0..5. chunk = e14..23 (identity).
// T1 (2 rounds by e13 = reg bit 4 both sides; identity map):
//   L1: regs k = (e5..8 @0..3, e13@4), lane = (e0..4, e9@5), w = e10..12.
// scs/scc indexed by (q - 10).
template <bool SQUARE>
__device__ __forceinline__ void p23_tail(float (&a)[32], float* __restrict__ lds,
                                         float* __restrict__ base,
                                         const float* __restrict__ scs,
                                         const float* __restrict__ scc,
                                         int lane, int w, int c14) {
    // phase 1: qubits 10..14 on L0 regs
    pair_bit32<4>(a, scs[0], scc[0], c14);       // q10: tgt e13, ctrl e14
    quad_gate32<3>(a, scs[1], scc[1]);           // q11: tgt e12 ctrl e13
    quad_gate32<2>(a, scs[2], scc[2]);
    quad_gate32<1>(a, scs[3], scc[3]);
    quad_gate32<0>(a, scs[4], scc[4]);           // q14: tgt e9 ctrl e10

    // T1: rounds x = e13; write identity h = lane | w<<6 | j<<9 (h = e0..12)
#pragma unroll
    for (int x = 0; x < 2; ++x) {
        if (x) __syncthreads();
#pragma unroll
        for (int j = 0; j < 16; ++j)
            lds[lane | (w << 6) | (j << 9)] = a[(x << 4) | j];
        __syncthreads();
#pragma unroll
        for (int m = 0; m < 16; ++m)
            a[(x << 4) | m] = lds[(lane & 31) | ((m & 1) << 5) | (((m >> 1) & 7) << 6)
                                  | ((lane >> 5) << 9) | (w << 10)];
    }

    // phase 2: qubits 15..18 on L1 regs (k0..k3 = e5..e8)
    pair_bit32<3>(a, scs[5], scc[5], (lane >> 5) & 1);  // q15: tgt e8 ctrl e9
    quad_gate32<2>(a, scs[6], scc[6]);                  // q16: tgt e7 ctrl e8
    quad_gate32<1>(a, scs[7], scc[7]);                  // q17: tgt e6 ctrl e7
    quad_gate32<0>(a, scs[8], scc[8]);                  // q18: tgt e5 ctrl e6

    // phase 3: lane gates.
    // q19: tgt e4 (mask 16, ds_swizzle), ctrl e5 = reg bit0
    lane_gate32_regctrl<16>(a, scs[9], scc[9], lane, (lane >> 4) & 1);
    lane_gate32<8>(a, scs[10], scc[10], lane);   // q20 (DPP row_ror:8)
    lane_gate32<4>(a, scs[11], scc[11], lane);   // q21 (DPP shr4/shl4 + select)
    lane_gate32<2>(a, scs[12], scc[12], lane);   // q22 (DPP quad_perm)
    lane_gate32<1>(a, scs[13], scc[13], lane);   // q23 (DPP quad_perm)

    if (SQUARE) {
#pragma unroll
        for (int r = 0; r < 32; ++r) a[r] *= a[r];
    }

    // store STANDARD from L1 (14-bit in-chunk addr):
    // addr = e0..4 | e5..8(k&15)<<5 | e9(lane5)<<9 | e10..12(w)<<10 | e13(k4)<<13
#pragma unroll
    for (int k = 0; k < 32; ++k)
        base[(lane & 31) | ((k & 15) << 5) | (((lane >> 5) & 1) << 9)
             | (w << 10) | (((k >> 4) & 1) << 13)] = a[k];
}

// P23: read pi2 from src, write standard to dst. chunk = e14..23 identity.
template <bool SQUARE>
__global__ __launch_bounds__(512, 4)
void pass23_pi_kernel(const float* __restrict__ src, float* __restrict__ dst,
                      const float* __restrict__ angles, int blk_b) {
    __shared__ float lds[8192];
    __shared__ float scs[14], scc[14];
    const int tid  = threadIdx.x;
    const int lane = tid & 63;
    const int w    = tid >> 6;
    const int chunk = blockIdx.x;                // 10 bits, bit k = e(14+k)
    float* __restrict__ base = dst + ((size_t)chunk << 14);
    const int c14 = chunk & 1;                   // e14
    const float* ang = angles + blk_b * N_QUBITS;

    if (tid < 14) {
        float s, c;
        sincosf(0.5f * ang[10 + tid], &s, &c);
        scs[tid] = s; scc[tid] = c;
    }

    float a[32];
    // read pi2: addr = (blk = r<<4 | w<<1 | e5)<<15 | chunk<<5 | e0..4
#pragma unroll
    for (int r = 0; r < 32; ++r)
        a[r] = src[((size_t)((r << 4) | (w << 1) | (lane >> 5)) << 15)
                   | ((size_t)chunk << 5) | (size_t)(lane & 31)];
    __syncthreads();                             // table ready

    p23_tail<SQUARE>(a, lds, base, scs, scc, lane, w, c14);
}

extern "C" void kernel_launch(void* const* d_in, const int* in_sizes, int n_in,
                              void* d_out, int out_size, void* d_ws, size_t ws_size,
                              hipStream_t stream) {
    const float* angles = (const float*)d_in[0];
    float* out = (float*)d_out;
    float* ws  = (float*)d_ws;

    // block 0 (analytic) + block 1 qubits 0..9 -> ws (pi2); no global reads
    fused_init_p1_kernel<<<512, 1024, 0, stream>>>(ws, angles);
    pass23_pi_kernel<false><<<1024, 512, 0, stream>>>(ws, out, angles, 1);

    pass1_pi_kernel<<<512, 1024, 0, stream>>>(out, ws, angles, 2);
    pass23_pi_kernel<false><<<1024, 512, 0, stream>>>(ws, out, angles, 2);

    pass1_pi_kernel<<<512, 1024, 0, stream>>>(out, ws, angles, 3);
    pass23_pi_kernel<true><<<1024, 512, 0, stream>>>(ws, out, angles, 3);
}